// Round 8
// baseline (265.200 us; speedup 1.0000x reference)
//
#include <hip/hip_runtime.h>
#include <hip/hip_bf16.h>

// Shapes: B=1024, C_CLS=80, D_WORD=300 (pad 384), J=8000, IMG_CH=2048
// out = feature @ H^T + r;  H = P @ W_img;  r = P @ b_img
// P = x2 @ W_cls^T + b_cls; x2 = adj @ t2; t2 = x1 @ Wgc2; x1 = leaky(adj @ t1); t1 = x0 @ Wgc1

typedef __bf16 bf16_t;
typedef __bf16 bf16x8 __attribute__((ext_vector_type(8)));
typedef float f32x4 __attribute__((ext_vector_type(4)));

#define MFMA16(a, b, c) __builtin_amdgcn_mfma_f32_16x16x32_bf16((a), (b), (c), 0, 0, 0)

// async global->LDS, 16B per lane; LDS dest is wave-uniform base + lane*16 (linear)
#define GLOAD_LDS16(g, l)                                     \
  __builtin_amdgcn_global_load_lds(                           \
      (const __attribute__((address_space(1))) void*)(g),     \
      (__attribute__((address_space(3))) void*)(l), 16, 0, 0)

// Issue-order pin: vmcnt counting is only valid if machine order == source order.
#define PIN()                                   \
  do {                                          \
    asm volatile("" ::: "memory");              \
    __builtin_amdgcn_sched_barrier(0);          \
  } while (0)

__device__ inline bf16x8 cvt8(float4 a, float4 b) {
  bf16x8 v;
  v[0] = (bf16_t)a.x; v[1] = (bf16_t)a.y; v[2] = (bf16_t)a.z; v[3] = (bf16_t)a.w;
  v[4] = (bf16_t)b.x; v[5] = (bf16_t)b.y; v[6] = (bf16_t)b.z; v[7] = (bf16_t)b.w;
  return v;
}

// ---- fused prep: adj + x0b convert + zero(t2,H,Ptmp,r,out) ----
__global__ __launch_bounds__(256) void k_prep(
    const float* __restrict__ A, const float* __restrict__ inp0,
    float* __restrict__ adj, bf16_t* __restrict__ x0b,
    float* __restrict__ t2, float* __restrict__ H,
    float* __restrict__ Ptmp, float* __restrict__ r, float* __restrict__ out) {
  int b = blockIdx.x, tid = threadIdx.x;
  if (b == 0) {
    __shared__ float Dv[80];
    if (tid < 80) {
      float s = 0.f;
      #pragma unroll 4
      for (int j = 0; j < 80; ++j) s += A[tid * 80 + j];
      Dv[tid] = rsqrtf(s);
    }
    __syncthreads();
    for (int idx = tid; idx < 6400; idx += 256) {
      int i = idx / 80, j = idx % 80;
      adj[idx] = Dv[i] * Dv[j] * A[j * 80 + i];
    }
  } else if (b <= 120) {
    int idx = (b - 1) * 256 + tid;
    if (idx < 30720) {
      int c = idx / 384, k = idx % 384;
      x0b[idx] = (k < 300) ? (bf16_t)inp0[c * 300 + k] : (bf16_t)0.f;
    }
  } else {
    // 79 blocks zero: t2(40960 f4), H(40960 f4), out(20480 f4), Ptmp(160000 f4), r(20 f4)
    int t = (b - 121) * 256 + tid;
    const int NT = 79 * 256;
    float4 z = make_float4(0.f, 0.f, 0.f, 0.f);
    for (int i = t; i < 40960; i += NT) ((float4*)t2)[i] = z;
    for (int i = t; i < 40960; i += NT) ((float4*)H)[i] = z;
    for (int i = t; i < 20480; i += NT) ((float4*)out)[i] = z;
    for (int i = t; i < 160000; i += NT) ((float4*)Ptmp)[i] = z;
    if (t < 20) ((float4*)r)[t] = z;
  }
}

// ---- t1 = x0 @ Wgc1 : [80,1024], K=300 padded to 384 ---- (R7 verbatim)
__global__ __launch_bounds__(256) void k_gc1m(
    const bf16_t* __restrict__ x0b, const float* __restrict__ Wgc1,
    float* __restrict__ t1) {
  int tid = threadIdx.x;
  int w = tid >> 6, l = tid & 63;
  int ln = l & 15, q = l >> 4;
  int n0 = blockIdx.x * 16;

  __shared__ float red[4][80][16];
  f32x4 acc[5] = {};
  for (int ks = 0; ks < 3; ++ks) {
    int kq = w * 96 + ks * 32 + q * 8;
    bf16x8 bfrag;
    #pragma unroll
    for (int jj = 0; jj < 8; ++jj) {
      int k = kq + jj;
      int kc = k < 300 ? k : 299;
      float wv = Wgc1[kc * 1024 + n0 + ln];
      bfrag[jj] = (bf16_t)(k < 300 ? wv : 0.f);
    }
    #pragma unroll
    for (int mt = 0; mt < 5; ++mt) {
      bf16x8 afrag = *(const bf16x8*)(x0b + (size_t)(mt * 16 + ln) * 384 + kq);
      acc[mt] = MFMA16(afrag, bfrag, acc[mt]);
    }
  }
  #pragma unroll
  for (int mt = 0; mt < 5; ++mt)
    #pragma unroll
    for (int reg = 0; reg < 4; ++reg)
      red[w][mt * 16 + q * 4 + reg][ln] = acc[mt][reg];
  __syncthreads();
  for (int o = tid; o < 1280; o += 256) {
    int c = o >> 4, nn = o & 15;
    t1[c * 1024 + n0 + nn] = red[0][c][nn] + red[1][c][nn] + red[2][c][nn] + red[3][c][nn];
  }
}

// ---- x1b = bf16(leaky_relu(adj @ t1, 0.2)) : [80,1024] ---- (R7 verbatim)
__global__ void k_adjmul_leaky(const float* __restrict__ adj, const float* __restrict__ t1,
                               bf16_t* __restrict__ x1b) {
  int idx = blockIdx.x * blockDim.x + threadIdx.x;  // 81920
  int c = idx >> 10, n = idx & 1023;
  const float* ar = adj + c * 80;
  float acc = 0.f;
  #pragma unroll 4
  for (int cc = 0; cc < 80; ++cc) acc += ar[cc] * t1[cc * 1024 + n];
  x1b[idx] = (bf16_t)(acc > 0.f ? acc : 0.2f * acc);
}

// ---- t2 += x1 @ Wgc2 : [80,2048], K=1024 ---- (R7 verbatim)
__global__ __launch_bounds__(256) void k_gc2m(
    const bf16_t* __restrict__ x1b, const float* __restrict__ Wgc2,
    float* __restrict__ t2) {
  int tid = threadIdx.x;
  int w = tid >> 6, l = tid & 63;
  int ln = l & 15, q = l >> 4;
  int nc = blockIdx.x & 31, kc = blockIdx.x >> 5;

  __shared__ float BsF[2 * 2048];
  auto stage = [&](int b, int k0) {
    #pragma unroll
    for (int it = 0; it < 2; ++it) {
      int slot = tid + it * 256;
      int kr = slot >> 4, nq = slot & 15;
      const float* src = Wgc2 + (size_t)(k0 + kr) * 2048 + nc * 64 + nq * 4;
      float* dst = BsF + b * 2048 + slot * 4;
      GLOAD_LDS16(src, dst);
    }
  };

  int kb = kc * 64;
  bf16x8 a0[5], a1[5];
  #pragma unroll
  for (int mt = 0; mt < 5; ++mt)
    a0[mt] = *(const bf16x8*)(x1b + (size_t)(mt * 16 + ln) * 1024 + kb + q * 8);
  PIN();
  stage(0, kb);
  PIN();
  stage(1, kb + 32);
  PIN();
  #pragma unroll
  for (int mt = 0; mt < 5; ++mt)
    a1[mt] = *(const bf16x8*)(x1b + (size_t)(mt * 16 + ln) * 1024 + kb + 32 + q * 8);
  PIN();

  f32x4 acc[5] = {};
  asm volatile("s_waitcnt vmcnt(7)" ::: "memory");
  PIN();
  __builtin_amdgcn_s_barrier();
  PIN();
  {
    bf16x8 bfrag;
    #pragma unroll
    for (int jj = 0; jj < 8; ++jj) bfrag[jj] = (bf16_t)BsF[(q * 8 + jj) * 64 + w * 16 + ln];
    #pragma unroll
    for (int mt = 0; mt < 5; ++mt) acc[mt] = MFMA16(a0[mt], bfrag, acc[mt]);
  }
  asm volatile("s_waitcnt vmcnt(5)" ::: "memory");
  PIN();
  __builtin_amdgcn_s_barrier();
  PIN();
  {
    bf16x8 bfrag;
    #pragma unroll
    for (int jj = 0; jj < 8; ++jj)
      bfrag[jj] = (bf16_t)BsF[2048 + (q * 8 + jj) * 64 + w * 16 + ln];
    #pragma unroll
    for (int mt = 0; mt < 5; ++mt) acc[mt] = MFMA16(a1[mt], bfrag, acc[mt]);
  }

  #pragma unroll
  for (int mt = 0; mt < 5; ++mt)
    #pragma unroll
    for (int reg = 0; reg < 4; ++reg)
      atomicAdd(&t2[(size_t)(mt * 16 + q * 4 + reg) * 2048 + nc * 64 + w * 16 + ln],
                acc[mt][reg]);
}

// ---- x2 = bf16(adj @ t2) : [80,2048] ---- (R7 verbatim)
__global__ void k_adjmul_bf16(const float* __restrict__ adj, const float* __restrict__ t2,
                              bf16_t* __restrict__ x2) {
  int idx = blockIdx.x * blockDim.x + threadIdx.x;  // 163840
  int c = idx >> 11, n = idx & 2047;
  const float* ar = adj + c * 80;
  float acc = 0.f;
  #pragma unroll 4
  for (int cc = 0; cc < 80; ++cc) acc += ar[cc] * t2[cc * 2048 + n];
  x2[idx] = (bf16_t)acc;
}

// ---- Ptmp += x2 @ W_cls^T (+bcls on kc==0) : [80,8000] fp32 ----
// R8 k-split x4 for TLP: grid 2000 = 500 j-chunks(16) x 4 k-chunks(512).
// Per-wave chain is 4 k-steps (was 16); 8 blocks/CU (LDS 20KB) -> ~full occ.
// The compiler can't undo TLP (unlike the 5 failed ILP schemes, VGPR 36-68).
__global__ __launch_bounds__(256) void k_clsproj(
    const float* __restrict__ Wcls, const float* __restrict__ bcls,
    const bf16_t* __restrict__ x2, float* __restrict__ Ptmp) {
  int tid = threadIdx.x;
  int w = tid >> 6, l = tid & 63;
  int ln = l & 15, q = l >> 4;
  int kc = blockIdx.x & 3;
  int j0 = (blockIdx.x >> 2) * 16;
  size_t jrow = (size_t)(j0 + ln) * 2048;

  __shared__ float red[4][80][16];
  f32x4 acc[5] = {};
  int kbase = kc * 512 + w * 128 + q * 8;
  #pragma unroll
  for (int ks = 0; ks < 4; ++ks) {
    int kq = kbase + ks * 32;
    const float4* bp = (const float4*)(Wcls + jrow + kq);
    float4 b0 = bp[0], b1 = bp[1];
    bf16x8 bfrag = cvt8(b0, b1);
    #pragma unroll
    for (int mt = 0; mt < 5; ++mt) {
      bf16x8 afrag = *(const bf16x8*)(x2 + (size_t)(mt * 16 + ln) * 2048 + kq);
      acc[mt] = MFMA16(afrag, bfrag, acc[mt]);
    }
  }
  #pragma unroll
  for (int mt = 0; mt < 5; ++mt)
    #pragma unroll
    for (int reg = 0; reg < 4; ++reg)
      red[w][mt * 16 + q * 4 + reg][ln] = acc[mt][reg];
  __syncthreads();

  for (int o = tid; o < 1280; o += 256) {
    int c = o >> 4, jj = o & 15;
    float v = red[0][c][jj] + red[1][c][jj] + red[2][c][jj] + red[3][c][jj];
    if (kc == 0) v += bcls[j0 + jj];
    atomicAdd(&Ptmp[(size_t)c * 8000 + j0 + jj], v);
  }
}

// ---- epilogue: P = bf16(Ptmp); r[c] = sum_j bimg[j]*Ptmp[c][j] ----
__global__ __launch_bounds__(256) void k_pfin(
    const float* __restrict__ Ptmp, const float* __restrict__ bimg,
    bf16_t* __restrict__ P, float* __restrict__ r) {
  __shared__ float rloc[80];
  int tid = threadIdx.x;
  if (tid < 80) rloc[tid] = 0.f;
  __syncthreads();
  for (int i = blockIdx.x * 256 + tid; i < 160000; i += 200 * 256) {
    int c = i / 2000, jq = i % 2000;            // float offset 4i = c*8000 + jq*4
    float4 v = ((const float4*)Ptmp)[i];
    float4 b = ((const float4*)bimg)[jq];
    bf16_t p4[4] = {(bf16_t)v.x, (bf16_t)v.y, (bf16_t)v.z, (bf16_t)v.w};
    __builtin_memcpy(P + (size_t)c * 8000 + jq * 4, p4, 8);
    atomicAdd(&rloc[c], v.x * b.x + v.y * b.y + v.z * b.z + v.w * b.w);
  }
  __syncthreads();
  if (tid < 80) atomicAdd(&r[tid], rloc[tid]);
}

// ---- H[c][n] += sum_j P[c][j]*W_img[j][n] ---- (R3 structure; R8: ping-pong
// aF[s&1] replaces the aCur=aNxt copy, which made the compiler wait on the
// NEWEST loads each iter (pipeline depth ~0). Static indices under unroll.)
__global__ __launch_bounds__(256) void k_hmat(
    const float* __restrict__ Wimg, const bf16_t* __restrict__ P, float* __restrict__ H) {
  int tid = threadIdx.x;
  int w = tid >> 6, l = tid & 63;
  int ln = l & 15, q = l >> 4;
  int jc = blockIdx.x >> 4, ncg = blockIdx.x & 15;
  int jbase = jc * 320;
  int n0 = (ncg * 4 + w) * 32;

  __shared__ float Bs[4 * 3 * 1024];  // 4 waves x ring-3 x (32j x 32n fp32) = 48 KB
  float* Bw = Bs + w * 3072;

  auto stage = [&](int buf, int jt) {
    #pragma unroll
    for (int it = 0; it < 4; ++it) {
      int row = it * 8 + (l >> 3);
      const float* src = Wimg + (size_t)(jt + row) * 2048 + n0 + (l & 7) * 4;
      float* dst = Bw + buf * 1024 + it * 256 + l * 4;
      GLOAD_LDS16(src, dst);
    }
  };
  auto loadA = [&](bf16x8* a, int j0) {
    #pragma unroll
    for (int mt = 0; mt < 5; ++mt)
      a[mt] = *(const bf16x8*)(P + (size_t)(mt * 16 + ln) * 8000 + j0 + q * 8);
  };

  f32x4 acc[5][2] = {};
  bf16x8 aF[2][5];

  loadA(aF[0], jbase);     // A(0)
  PIN();
  stage(0, jbase);         // B(0)
  PIN();
  stage(1, jbase + 32);    // B(1)
  PIN();

  #pragma unroll
  for (int s = 0; s < 10; ++s) {
    if (s < 9) {
      loadA(aF[(s + 1) & 1], jbase + (s + 1) * 32);   // A(s+1)
      PIN();
    }
    if (s < 8) {
      stage((s + 2) % 3, jbase + (s + 2) * 32);       // B(s+2)
      PIN();
    }
    // wait for A(s)+B(s): FIFO leaves B(s+1)4 + A(s+1)5 + B(s+2)4 = 13 in flight
    if (s < 8)       asm volatile("s_waitcnt vmcnt(13)" ::: "memory");
    else if (s == 8) asm volatile("s_waitcnt vmcnt(9)"  ::: "memory");
    else             asm volatile("s_waitcnt vmcnt(0)"  ::: "memory");
    PIN();  // no barrier — buffer is wave-private
    const float* Bc = Bw + (s % 3) * 1024;
    bf16x8 bfrag[2];
    #pragma unroll
    for (int nt = 0; nt < 2; ++nt)
      #pragma unroll
      for (int jj = 0; jj < 8; ++jj)
        bfrag[nt][jj] = (bf16_t)Bc[(q * 8 + jj) * 32 + nt * 16 + ln];
    #pragma unroll
    for (int mt = 0; mt < 5; ++mt)
      #pragma unroll
      for (int nt = 0; nt < 2; ++nt)
        acc[mt][nt] = MFMA16(aF[s & 1][mt], bfrag[nt], acc[mt][nt]);
    PIN();  // keep cvt/MFMA ahead of next iter's restage of buf[s%3]
  }

  #pragma unroll
  for (int mt = 0; mt < 5; ++mt)
    #pragma unroll
    for (int nt = 0; nt < 2; ++nt)
      #pragma unroll
      for (int reg = 0; reg < 4; ++reg)
        atomicAdd(&H[(size_t)(mt * 16 + q * 4 + reg) * 2048 + n0 + nt * 16 + ln],
                  acc[mt][nt][reg]);
}

// ---- out[b][c] += sum_k feature[b][k]*H[c][k]  (+ r[c] once) ---- (R7 verbatim)
__global__ __launch_bounds__(256) void k_out(
    const float* __restrict__ feat, const float* __restrict__ H,
    const float* __restrict__ r, float* __restrict__ out) {
  int tid = threadIdx.x;
  int w = tid >> 6, l = tid & 63;
  int ln = l & 15, q = l >> 4;
  int mg = blockIdx.x & 15, kc = blockIdx.x >> 4;
  int m0 = mg * 64 + w * 16;
  size_t frow = (size_t)(m0 + ln) * 2048;

  f32x4 acc[5] = {};
  int kbase = kc * 64 + q * 8;
  #pragma unroll
  for (int ks = 0; ks < 2; ++ks) {
    int kq = kbase + ks * 32;
    const float4* ap = (const float4*)(feat + frow + kq);
    bf16x8 afrag = cvt8(ap[0], ap[1]);
    #pragma unroll
    for (int nt = 0; nt < 5; ++nt) {
      const float4* hp = (const float4*)(H + (size_t)(nt * 16 + ln) * 2048 + kq);
      bf16x8 bfrag = cvt8(hp[0], hp[1]);
      acc[nt] = MFMA16(afrag, bfrag, acc[nt]);
    }
  }
  #pragma unroll
  for (int nt = 0; nt < 5; ++nt)
    #pragma unroll
    for (int reg = 0; reg < 4; ++reg) {
      int b = m0 + q * 4 + reg;
      int c = nt * 16 + ln;
      float v = acc[nt][reg];
      if (kc == 0) v += r[c];
      atomicAdd(&out[b * 80 + c], v);
    }
}

extern "C" void kernel_launch(void* const* d_in, const int* in_sizes, int n_in,
                              void* d_out, int out_size, void* d_ws, size_t ws_size,
                              hipStream_t stream) {
  const float* feature = (const float*)d_in[0];
  const float* inp     = (const float*)d_in[1];  // [1,80,300]
  const float* A       = (const float*)d_in[2];
  const float* Wgc1    = (const float*)d_in[3];
  const float* Wgc2    = (const float*)d_in[4];
  const float* Wimg    = (const float*)d_in[5];
  const float* bimg    = (const float*)d_in[6];
  const float* Wcls    = (const float*)d_in[7];
  const float* bcls    = (const float*)d_in[8];
  float* out = (float*)d_out;

  char* ws = (char*)d_ws;
  float*  adj  = (float*)(ws + 0);         //  80x80    fp32     25,600
  float*  t1   = (float*)(ws + 25600);     //  80x1024  fp32    327,680
  bf16_t* x1b  = (bf16_t*)(ws + 353280);   //  80x1024  bf16    163,840
  float*  t2   = (float*)(ws + 517120);    //  80x2048  fp32    655,360
  bf16_t* x2   = (bf16_t*)(ws + 1172480);  //  80x2048  bf16    327,680
  bf16_t* P    = (bf16_t*)(ws + 1500160);  //  80x8000  bf16  1,280,000
  float*  H    = (float*)(ws + 2780160);   //  80x2048  fp32    655,360
  float*  r    = (float*)(ws + 3435520);   //  80       fp32        320
  bf16_t* x0b  = (bf16_t*)(ws + 3435840);  //  80x384   bf16     61,440
  float*  Ptmp = (float*)(ws + 3497280);   //  80x8000  fp32  2,560,000

  // 9 dispatches (launch overhead ~3us each per R7 A/B)
  k_prep<<<200, 256, 0, stream>>>(A, inp, adj, x0b, t2, H, Ptmp, r, out);
  k_gc1m<<<64, 256, 0, stream>>>(x0b, Wgc1, t1);
  k_adjmul_leaky<<<320, 256, 0, stream>>>(adj, t1, x1b);
  k_gc2m<<<512, 256, 0, stream>>>(x1b, Wgc2, t2);
  k_adjmul_bf16<<<640, 256, 0, stream>>>(adj, t2, x2);
  k_clsproj<<<2000, 256, 0, stream>>>(Wcls, bcls, x2, Ptmp);
  k_pfin<<<200, 256, 0, stream>>>(Ptmp, bimg, P, r);
  k_hmat<<<400, 256, 0, stream>>>(Wimg, P, H);
  k_out<<<512, 256, 0, stream>>>(feature, H, r, out);
}